// Round 13
// baseline (2966.317 us; speedup 1.0000x reference)
//
#include <hip/hip_runtime.h>
#include <hip/hip_bf16.h>

// RNN_46548855554081: 2-layer tanh RNN, B=64, T=512, H=1024, IN=64, OUT=1.
// R13: per-wave DATAFLOW, no __syncthreads in the loop. R12 showed the step is
// latency-bound (read-volume 3x cut -> only -12%): the WG lockstep + 4 barriers
// + staging serialization dominate. Now 256 WGs x 192 thr (3 waves):
//   wave0: L1 full-K (34 frags) -> h1, flags fh1      (the critical cycle)
//   wave1: W_ih1*h1[s-1] -> pc via LDS handshake
//   wave2: W_hh1*h2[s-2] + pc -> h2, flags fh2        (parallel lagging cycle)
// h traffic write-through/read-through agent-scope (R11-proven, no fences).
// wave0 joins wave1's h1done (LDS) before fh1 -> buffer parity reuse is safe.

typedef float f32x4 __attribute__((ext_vector_type(4)));
typedef _Float16 half8 __attribute__((ext_vector_type(8)));

#define T_STEPS 512

// ws layout (bytes)
#define FH1_OFF   0                        // 256 slots x 64B  (prep: 0)
#define FH2_OFF   16384                    // 256 slots x 64B  (prep: 1)
#define XT_OFF    32768                    // [512][4][8kg][16row][8] f16 = 4 MB
#define H1_OFF    (XT_OFF + 4194304)       // [2buf][4g][128kg][16row][8] f16 = 256 KB
#define H2_OFF    (H1_OFF + 262144)        // same, 256 KB
#define H2T0_OFF  (H2_OFF + 262144)        // [64][1024] f32 = 256 KB (h2 at t=0)

#define SPIN_CAP (1u << 20)

__device__ inline float tanh_fast(float z) {
  z = fminf(20.f, fmaxf(-20.f, z));
  float e = __expf(2.f * z);
  return (e - 1.f) / (e + 1.f);
}

__device__ inline half8 ldw8(const float* p) {
  half8 r;
#pragma unroll
  for (int i = 0; i < 8; ++i) r[i] = (_Float16)p[i];
  return r;
}

// coherent (agent-scope, relaxed) 16B fragment load: 2 x u64 atomic loads
__device__ inline half8 ldh8_coh(const _Float16* p) {
  union { unsigned long long q[2]; half8 h; } u;
  unsigned long long* a = (unsigned long long*)p;
  u.q[0] = __hip_atomic_load(a,     __ATOMIC_RELAXED, __HIP_MEMORY_SCOPE_AGENT);
  u.q[1] = __hip_atomic_load(a + 1, __ATOMIC_RELAXED, __HIP_MEMORY_SCOPE_AGENT);
  return u.h;
}

__device__ inline void sth_coh(_Float16* p, float v) {
  union { _Float16 h; unsigned short u; } cv;
  cv.h = (_Float16)v;
  __hip_atomic_store((unsigned short*)p, cv.u, __ATOMIC_RELAXED, __HIP_MEMORY_SCOPE_AGENT);
}

// 64-lane gather-poll on a global flag array (one slot per lane), target t
__device__ inline void poll_flags(int* base, int lane, int t) {
  int* f = base + (size_t)lane * 16;   // 64B stride
  unsigned spins = 0;
  for (;;) {
    int v = __hip_atomic_load(f, __ATOMIC_RELAXED, __HIP_MEMORY_SCOPE_AGENT);
    if (__all(v >= t)) break;
    __builtin_amdgcn_s_sleep(1);
    if (++spins > SPIN_CAP) break;     // safety valve: wrong answer, not a hang
  }
  asm volatile("" ::: "memory");       // no compiler hoist of data loads above poll
}

// ---- prep: tile x into f16 fragment layout [t][g][kg(8)][16row][8] ----
__global__ void prep_x(const float* __restrict__ x, _Float16* __restrict__ xt) {
  int i = blockIdx.x * 256 + threadIdx.x;       // 2^21 elements
  int j = i & 7;
  int row = (i >> 3) & 15;
  int kgv = (i >> 7) & 7;
  int gg = (i >> 10) & 3;
  int t = i >> 12;
  int b = gg * 16 + row;
  xt[i] = (_Float16)x[(b * 512 + t) * 64 + kgv * 8 + j];
}

// ---- prep: tile h_state into h buffers (parity 1), init flags (fh1=0, fh2=1) ----
__global__ void prep_h(const float* __restrict__ hs, _Float16* __restrict__ h1b,
                       _Float16* __restrict__ h2b, char* __restrict__ wsbase) {
  int i = blockIdx.x * 256 + threadIdx.x;       // 2^17 elements
  int j = i & 7;
  int row = (i >> 3) & 15;
  int kgv = (i >> 7) & 127;
  int gg = (i >> 14) & 3;
  int l = i >> 16;
  int b = gg * 16 + row;
  int h = kgv * 8 + j;
  float v = hs[(size_t)l * 65536 + b * 1024 + h];
  _Float16* dst = l ? h2b : h1b;
  dst[(size_t)(4 + gg) * 16384 + (kgv * 16 + row) * 8 + j] = (_Float16)v;
  if (i < 512) *(int*)(wsbase + (size_t)i * 64) = (i >= 256) ? 1 : 0;
}

// ---- persistent dataflow scan: 256 WGs x 192 thr (3 waves, no loop barriers) ----
__global__ __launch_bounds__(192, 1) void rnn_persist(
    const float* __restrict__ Wih0, const float* __restrict__ Whh0,
    const float* __restrict__ bih0, const float* __restrict__ bhh0,
    const float* __restrict__ Wih1, const float* __restrict__ Whh1,
    const float* __restrict__ bih1, const float* __restrict__ bhh1,
    const float* __restrict__ Wout, const float* __restrict__ bout,
    float* __restrict__ out, char* __restrict__ ws) {
  __shared__ float pcA[256];      // pc double-buffer (static indexing, rule #20)
  __shared__ float pcB[256];
  __shared__ int pcflag;          // wave1 -> wave2: pc[s] ready
  __shared__ int ackflag;         // wave2 -> wave1: pc[s] consumed
  __shared__ int h1done;          // wave1 -> wave0: done reading h1[s-1]

  const int bid = blockIdx.x;
  const int g = bid >> 6;          // batch group (16 batches)
  const int cu = bid & 63;         // owns columns [16cu, 16cu+16)
  const int tid = threadIdx.x;
  const int wave = tid >> 6;       // 0: L1, 1: W_ih1 pc, 2: W_hh1 + h2 owner
  const int lane = tid & 63;
  const int col = lane & 15;
  const int kg = lane >> 4;

  int* fh1 = (int*)(ws + FH1_OFF) + (size_t)g * 64 * 16;   // group's 64 slots
  int* fh2 = (int*)(ws + FH2_OFF) + (size_t)g * 64 * 16;
  const _Float16* xt = (const _Float16*)(ws + XT_OFF);
  _Float16* h1b = (_Float16*)(ws + H1_OFF);
  _Float16* h2b = (_Float16*)(ws + H2_OFF);
  float* h2t0 = (float*)(ws + H2T0_OFF);

  const int c = cu * 16 + col;

  if (tid == 0) { pcflag = 0; ackflag = 0; h1done = 0; }

  // ---- weights -> f16 register fragments (once) ----
  half8 bw[34];
  float bias = 0.f;
  if (wave == 0) {                 // L1 full K=1088 (x 64 + Whh0 1024)
#pragma unroll
    for (int f = 0; f < 34; ++f) {
      int k0 = f * 32 + kg * 8;
      const float* p = (k0 < 64) ? (Wih0 + c * 64 + k0) : (Whh0 + c * 1024 + (k0 - 64));
      bw[f] = ldw8(p);
    }
    bias = bih0[c] + bhh0[c];
  } else if (wave == 1) {          // W_ih1 full K=1024
#pragma unroll
    for (int f = 0; f < 32; ++f) bw[f] = ldw8(Wih1 + c * 1024 + f * 32 + kg * 8);
  } else {                         // W_hh1 full K=1024
#pragma unroll
    for (int f = 0; f < 32; ++f) bw[f] = ldw8(Whh1 + c * 1024 + f * 32 + kg * 8);
    bias = bih1[c] + bhh1[c];
  }
  __syncthreads();                 // LDS init + weights ready; last barrier.

  if (wave == 0) {
    // ======== h1 critical cycle: h1[s] = tanh(x[s] + Whh0 h1[s-1]) ========
    for (int s = 0; s < T_STEPS; ++s) {
      if (s > 0) poll_flags(fh1, lane, s);                  // h1[s-1] published
      const _Float16* h1rd = h1b + (size_t)(((s + 1) & 1) * 4 + g) * 16384;
      _Float16* h1wr = h1b + (size_t)((s & 1) * 4 + g) * 16384;
      const _Float16* xsrc = xt + (size_t)(s * 4 + g) * 1024;
      f32x4 acc = {0.f, 0.f, 0.f, 0.f};
#pragma unroll
      for (int f = 0; f < 34; ++f) {
        half8 a = (f < 2) ? *(const half8*)(xsrc + f * 512 + lane * 8)
                          : ldh8_coh(h1rd + (f - 2) * 512 + lane * 8);
        acc = __builtin_amdgcn_mfma_f32_16x16x32_f16(a, bw[f], acc, 0, 0, 0);
      }
#pragma unroll
      for (int r = 0; r < 4; ++r) {
        int row = kg * 4 + r;
        float h = tanh_fast(acc[r] + bias);
        sth_coh(h1wr + ((cu * 2 + (col >> 3)) * 16 + row) * 8 + (col & 7), h);
        if (s == T_STEPS - 1) out[64 + (g * 16 + row) * 1024 + c] = h;  // h_new[0]
      }
      asm volatile("s_waitcnt vmcnt(0)" ::: "memory");      // h1 stores committed
      {                                                     // join wave1's reads
        unsigned spins = 0;
        while (__hip_atomic_load(&h1done, __ATOMIC_ACQUIRE,
                                 __HIP_MEMORY_SCOPE_WORKGROUP) < s) {
          __builtin_amdgcn_s_sleep(1);
          if (++spins > SPIN_CAP) break;
        }
      }
      if (lane == 0)
        __hip_atomic_store(fh1 + (size_t)cu * 16, s + 1,
                           __ATOMIC_RELAXED, __HIP_MEMORY_SCOPE_AGENT);
    }
  } else if (wave == 1) {
    // ======== pc[s] = W_ih1 * h1[s-1]  (for h2[s-1]) ========
    for (int s = 1; s <= T_STEPS; ++s) {
      {                                                     // pc buffer free?
        unsigned spins = 0;
        while (__hip_atomic_load(&ackflag, __ATOMIC_ACQUIRE,
                                 __HIP_MEMORY_SCOPE_WORKGROUP) < s - 2) {
          __builtin_amdgcn_s_sleep(1);
          if (++spins > SPIN_CAP) break;
        }
      }
      poll_flags(fh1, lane, s);                             // h1[s-1] published
      const _Float16* h1rd = h1b + (size_t)(((s + 1) & 1) * 4 + g) * 16384;
      f32x4 acc = {0.f, 0.f, 0.f, 0.f};
#pragma unroll
      for (int f = 0; f < 32; ++f) {
        half8 a = ldh8_coh(h1rd + f * 512 + lane * 8);
        acc = __builtin_amdgcn_mfma_f32_16x16x32_f16(a, bw[f], acc, 0, 0, 0);
      }
      __hip_atomic_store(&h1done, s, __ATOMIC_RELEASE,      // done reading h1[s-1]
                         __HIP_MEMORY_SCOPE_WORKGROUP);
      float* pc = (s & 1) ? pcA : pcB;
#pragma unroll
      for (int r = 0; r < 4; ++r) pc[(kg * 4 + r) * 16 + col] = acc[r];
      __hip_atomic_store(&pcflag, s, __ATOMIC_RELEASE,
                         __HIP_MEMORY_SCOPE_WORKGROUP);
    }
  } else {
    // ======== h2 cycle: h2[s-1] = tanh(pc[s] + Whh1 h2[s-2]) ========
    for (int s = 1; s <= T_STEPS; ++s) {
      poll_flags(fh2, lane, s);                             // h2[s-2] published
      const _Float16* h2rd = h2b + (size_t)((s & 1) * 4 + g) * 16384;
      _Float16* h2wr = h2b + (size_t)(((s + 1) & 1) * 4 + g) * 16384;
      f32x4 acc = {0.f, 0.f, 0.f, 0.f};
#pragma unroll
      for (int f = 0; f < 32; ++f) {
        half8 a = ldh8_coh(h2rd + f * 512 + lane * 8);
        acc = __builtin_amdgcn_mfma_f32_16x16x32_f16(a, bw[f], acc, 0, 0, 0);
      }
      {                                                     // wait wave1's pc[s]
        unsigned spins = 0;
        while (__hip_atomic_load(&pcflag, __ATOMIC_ACQUIRE,
                                 __HIP_MEMORY_SCOPE_WORKGROUP) < s) {
          __builtin_amdgcn_s_sleep(1);
          if (++spins > SPIN_CAP) break;
        }
      }
      const float* pc = (s & 1) ? pcA : pcB;
#pragma unroll
      for (int r = 0; r < 4; ++r) {
        int row = kg * 4 + r;
        float h = tanh_fast(acc[r] + pc[row * 16 + col] + bias);
        sth_coh(h2wr + ((cu * 2 + (col >> 3)) * 16 + row) * 8 + (col & 7), h);
        if (s == 1)
          __hip_atomic_store((unsigned*)(h2t0 + (size_t)(g * 16 + row) * 1024 + c),
                             __float_as_uint(h), __ATOMIC_RELAXED,
                             __HIP_MEMORY_SCOPE_AGENT);
        if (s == T_STEPS) out[64 + 65536 + (g * 16 + row) * 1024 + c] = h;  // h_new[1]
      }
      __hip_atomic_store(&ackflag, s, __ATOMIC_RELEASE,     // pc[s] consumed
                         __HIP_MEMORY_SCOPE_WORKGROUP);
      asm volatile("s_waitcnt vmcnt(0)" ::: "memory");      // h2 stores committed
      if (lane == 0)
        __hip_atomic_store(fh2 + (size_t)cu * 16, s + 1,
                           __ATOMIC_RELAXED, __HIP_MEMORY_SCOPE_AGENT);
    }
    // ---- projection: out = r2[:,0,:] @ W_out^T + b_out (leader tile, 64 lanes) ----
    if (cu == 0) {
      const int b = lane & 15, q = lane >> 4;
      const float* hrow = h2t0 + (size_t)(g * 16 + b) * 1024 + q * 256;
      const float* wrow = Wout + q * 256;
      float sum = 0.f;
      for (int i = 0; i < 256; ++i) {
        unsigned u = __hip_atomic_load((unsigned*)(hrow + i), __ATOMIC_RELAXED,
                                       __HIP_MEMORY_SCOPE_AGENT);
        sum += __uint_as_float(u) * wrow[i];
      }
      sum += __shfl_xor(sum, 16);
      sum += __shfl_xor(sum, 32);
      if (q == 0) out[g * 16 + b] = sum + bout[0];
    }
  }
}

extern "C" void kernel_launch(void* const* d_in, const int* in_sizes, int n_in,
                              void* d_out, int out_size, void* d_ws, size_t ws_size,
                              hipStream_t stream) {
  const float* x    = (const float*)d_in[0];
  const float* hs   = (const float*)d_in[1];
  const float* Wih0 = (const float*)d_in[2];
  const float* Whh0 = (const float*)d_in[3];
  const float* bih0 = (const float*)d_in[4];
  const float* bhh0 = (const float*)d_in[5];
  const float* Wih1 = (const float*)d_in[6];
  const float* Whh1 = (const float*)d_in[7];
  const float* bih1 = (const float*)d_in[8];
  const float* bhh1 = (const float*)d_in[9];
  const float* Wout = (const float*)d_in[10];
  const float* bout = (const float*)d_in[11];
  float* out = (float*)d_out;
  char* ws = (char*)d_ws;

  _Float16* xt  = (_Float16*)(ws + XT_OFF);
  _Float16* h1b = (_Float16*)(ws + H1_OFF);
  _Float16* h2b = (_Float16*)(ws + H2_OFF);

  prep_x<<<8192, 256, 0, stream>>>(x, xt);
  prep_h<<<512, 256, 0, stream>>>(hs, h1b, h2b, ws);
  rnn_persist<<<256, 192, 0, stream>>>(Wih0, Whh0, bih0, bhh0,
                                       Wih1, Whh1, bih1, bhh1,
                                       Wout, bout, out, ws);
}